// Round 3
// baseline (612.361 us; speedup 1.0000x reference)
//
#include <hip/hip_runtime.h>
#include <hip/hip_bf16.h>

// MixedDimTableBatchedEmbeddingBags
// 8 tables, 250k rows, dims {16,32,64,128}x2, B=8192, L=32, fp32.
// out[b, c*4 + j] = sum_l W[woff_t + idx[t,b,l]*dim_t + (c-bound_t)*4 + j] * psw[t,b,l]
//
// One thread per output float4 (g = b*120 + c). Output writes perfectly
// coalesced. idx/psw loaded as int4/float4 (4x fewer broadcast loads than
// scalar). dim_t = 16<<(t&3) and woff_t = bound_t*1e6, so no per-lane
// constant-memory loads and row*dim is a shift.

#define BATCH    8192
#define BAG_L    32
#define GROUPS_PER_ROW 120                     // 480 floats / 4
#define TOTAL_GROUPS (BATCH * GROUPS_PER_ROW)  // 983040

typedef float  nfloat4 __attribute__((ext_vector_type(4)));  // native vec for nontemporal store

__constant__ int c_bound[8] = {0, 4, 12, 28, 60, 64, 72, 88};

__global__ __launch_bounds__(256) void emb_bags_kernel(
    const float* __restrict__ weights,
    const int*   __restrict__ indices,
    const float* __restrict__ psw,
    float*       __restrict__ out)
{
    const int g = blockIdx.x * blockDim.x + threadIdx.x;  // exact: grid*block == TOTAL_GROUPS
    const int b = g / GROUPS_PER_ROW;
    const int c = g - b * GROUPS_PER_ROW;

    // Table of this column group (branchless).
    const int t = (c >= 4) + (c >= 12) + (c >= 28) + (c >= 60)
                + (c >= 64) + (c >= 72) + (c >= 88);

    const int      bound = c_bound[t];
    const int      shift = 4 + (t & 3);                   // log2(dim): 16<<(t&3)
    const unsigned wbase = (unsigned)bound * 1000000u     // woff_t == bound_t * 1e6
                         + (unsigned)(c - bound) * 4u;
    const int      ibase = (t * BATCH + b) * BAG_L;       // 128B-aligned

    const int4*   idx4 = (const int4*)(indices + ibase);
    const float4* pw4  = (const float4*)(psw + ibase);

    float4 acc0 = make_float4(0.f, 0.f, 0.f, 0.f);
    float4 acc1 = make_float4(0.f, 0.f, 0.f, 0.f);

#pragma unroll
    for (int q = 0; q < BAG_L / 4; ++q) {
        const int4   iv = idx4[q];
        const float4 wv = pw4[q];
        const float4 v0 = *(const float4*)(weights + (size_t)(wbase + ((unsigned)iv.x << shift)));
        const float4 v1 = *(const float4*)(weights + (size_t)(wbase + ((unsigned)iv.y << shift)));
        const float4 v2 = *(const float4*)(weights + (size_t)(wbase + ((unsigned)iv.z << shift)));
        const float4 v3 = *(const float4*)(weights + (size_t)(wbase + ((unsigned)iv.w << shift)));
        acc0.x += v0.x * wv.x; acc0.y += v0.y * wv.x; acc0.z += v0.z * wv.x; acc0.w += v0.w * wv.x;
        acc1.x += v1.x * wv.y; acc1.y += v1.y * wv.y; acc1.z += v1.z * wv.y; acc1.w += v1.w * wv.y;
        acc0.x += v2.x * wv.z; acc0.y += v2.y * wv.z; acc0.z += v2.z * wv.z; acc0.w += v2.w * wv.z;
        acc1.x += v3.x * wv.w; acc1.y += v3.y * wv.w; acc1.z += v3.z * wv.w; acc1.w += v3.w * wv.w;
    }

    const nfloat4 r = { acc0.x + acc1.x, acc0.y + acc1.y,
                        acc0.z + acc1.z, acc0.w + acc1.w };
    // Write-once output: nontemporal to keep it out of L2.
    __builtin_nontemporal_store(r, (nfloat4*)out + g);
}

extern "C" void kernel_launch(void* const* d_in, const int* in_sizes, int n_in,
                              void* d_out, int out_size, void* d_ws, size_t ws_size,
                              hipStream_t stream) {
    const float* weights = (const float*)d_in[0];
    const int*   indices = (const int*)d_in[1];
    // d_in[2] = offsets (uniform stride L=32; encoded statically)
    const float* psw     = (const float*)d_in[3];
    float*       out     = (float*)d_out;

    const int block = 256;
    const int grid  = TOTAL_GROUPS / block;  // 3840
    emb_bags_kernel<<<grid, block, 0, stream>>>(weights, indices, psw, out);
}